// Round 4
// baseline (1353.378 us; speedup 1.0000x reference)
//
#include <hip/hip_runtime.h>
#include <math.h>

typedef __bf16 bf16;
typedef __attribute__((ext_vector_type(4))) __bf16 bf16x4;
typedef __attribute__((ext_vector_type(8))) __bf16 bf16x8;
typedef __attribute__((ext_vector_type(4))) float f32x4;

#define T_STEPS 128
#define B_SZ    256
#define V_SZ    256
#define N_SZ    1024
#define NROWS   (T_STEPS * B_SZ)   // 32768
#define LDSS    72                 // padded LDS stride (k_xproj)
#define RST     36                 // k_step reduction stride (floats)
#define AST     1032               // k_loss A LDS stride (bf16 elems; 2064 B, 16-B aligned rows)
#define CST     260                // k_loss logits stride (floats)

__device__ __forceinline__ float fast_tanh(float x) {
    float e = __expf(2.0f * x);
    return 1.0f - 2.0f / (e + 1.0f);   // exact at +-inf, no NaN
}

// ---------------- fp32 -> bf16 contiguous convert ----------------
__global__ void k_convert(const float* __restrict__ src, bf16* __restrict__ dst, int n) {
    int i = (blockIdx.x * blockDim.x + threadIdx.x) * 4;
    if (i < n) {
        float4 v = *(const float4*)(src + i);
        bf16x4 o;
        o.x = (bf16)v.x; o.y = (bf16)v.y; o.z = (bf16)v.z; o.w = (bf16)v.w;
        *(bf16x4*)(dst + i) = o;
    }
}

// ---------------- fp32 (R x C) -> bf16 transpose (C x R) ----------------
__global__ void k_transpose_cvt(const float* __restrict__ src, bf16* __restrict__ dst,
                                int R, int C) {
    __shared__ float tile[32][33];
    int c0 = blockIdx.x * 32;
    int r0 = blockIdx.y * 32;
    int tx = threadIdx.x & 31;
    int ty = threadIdx.x >> 5;   // 0..7
#pragma unroll
    for (int i = 0; i < 32; i += 8)
        tile[ty + i][tx] = src[(size_t)(r0 + ty + i) * C + c0 + tx];
    __syncthreads();
#pragma unroll
    for (int i = 0; i < 32; i += 8)
        dst[(size_t)(c0 + ty + i) * R + r0 + tx] = (bf16)tile[tx][ty + i];
}

// ---------------- Xproj: XH[i][n] = bf16( X[i]@Wx[:,n] + bias[n] ) ----------------
// Rows with i < B_SZ are t=0: fold in h0 = tanh(Xproj0) since h_init = 0.
__global__ __launch_bounds__(256) void k_xproj(
    const bf16* __restrict__ X, const bf16* __restrict__ Wxt,
    const float* __restrict__ bias, bf16* __restrict__ XH)
{
    __shared__ __align__(16) bf16 As[64 * LDSS];
    __shared__ __align__(16) bf16 Bs[64 * LDSS];
    const int tid  = threadIdx.x;
    const int lane = tid & 63;
    const int w    = tid >> 6;
    const int wm   = (w >> 1) * 32;
    const int wn   = (w & 1) * 32;
    const int quad = lane >> 4;
    const int l15  = lane & 15;
    const int m0 = blockIdx.x * 64;
    const int n0 = blockIdx.y * 64;

    const bf16* Ag = X + (size_t)m0 * V_SZ;
    const bf16* Bg = Wxt + (size_t)n0 * V_SZ;

    f32x4 z = {0.f, 0.f, 0.f, 0.f};
    f32x4 acc00 = z, acc01 = z, acc10 = z, acc11 = z;

    for (int k0 = 0; k0 < V_SZ; k0 += 64) {
        {
            int c = tid, row = c >> 3, col = (c & 7) * 8;
            *(bf16x8*)&As[row * LDSS + col] = *(const bf16x8*)&Ag[(size_t)row * V_SZ + k0 + col];
            *(bf16x8*)&Bs[row * LDSS + col] = *(const bf16x8*)&Bg[(size_t)row * V_SZ + k0 + col];
            c = tid + 256; row = c >> 3; col = (c & 7) * 8;
            *(bf16x8*)&As[row * LDSS + col] = *(const bf16x8*)&Ag[(size_t)row * V_SZ + k0 + col];
            *(bf16x8*)&Bs[row * LDSS + col] = *(const bf16x8*)&Bg[(size_t)row * V_SZ + k0 + col];
        }
        __syncthreads();
#pragma unroll
        for (int kc = 0; kc < 64; kc += 32) {
            bf16x8 a0 = *(const bf16x8*)&As[(wm + l15) * LDSS + kc + quad * 8];
            bf16x8 a1 = *(const bf16x8*)&As[(wm + 16 + l15) * LDSS + kc + quad * 8];
            bf16x8 b0 = *(const bf16x8*)&Bs[(wn + l15) * LDSS + kc + quad * 8];
            bf16x8 b1 = *(const bf16x8*)&Bs[(wn + 16 + l15) * LDSS + kc + quad * 8];
            acc00 = __builtin_amdgcn_mfma_f32_16x16x32_bf16(a0, b0, acc00, 0, 0, 0);
            acc01 = __builtin_amdgcn_mfma_f32_16x16x32_bf16(a0, b1, acc01, 0, 0, 0);
            acc10 = __builtin_amdgcn_mfma_f32_16x16x32_bf16(a1, b0, acc10, 0, 0, 0);
            acc11 = __builtin_amdgcn_mfma_f32_16x16x32_bf16(a1, b1, acc11, 0, 0, 0);
        }
        __syncthreads();
    }
    bf16* Out = XH + (size_t)m0 * N_SZ + n0;
    const f32x4 accs[2][2] = {{acc00, acc01}, {acc10, acc11}};
#pragma unroll
    for (int mi = 0; mi < 2; ++mi)
#pragma unroll
        for (int r = 0; r < 4; ++r) {
            int row = wm + mi * 16 + quad * 4 + r;
            bool is_t0 = (m0 + row) < B_SZ;   // t=0 rows: apply tanh (h_prev = 0)
#pragma unroll
            for (int ni = 0; ni < 2; ++ni) {
                int col = wn + ni * 16 + l15;
                float pre = accs[mi][ni][r] + bias[n0 + col];
                if (is_t0) pre = fast_tanh(pre);
                Out[(size_t)row * N_SZ + col] = (bf16)pre;
            }
        }
}

// ---------------- recurrent step: XH[t] = tanh(XH[t] + XH[t-1] @ Wh), t >= 1 --------
// Grid (32 n, 16 m) = 512 blocks (2/CU), 512 threads = 8 waves, K-split 128/wave.
// Tile 16 rows x 32 cols. B and A read straight from L2 into registers; LDS only
// for the 8-wave K-reduction. Xproj term prefetched at kernel start.
__global__ __launch_bounds__(512) void k_step(
    const bf16* __restrict__ Wht,   // 1024 x 1024 = Wh^T
    bf16* __restrict__ XH, int t)
{
    __shared__ float red[8 * 16 * RST];   // 18.4 KB
    const int tid  = threadIdx.x;
    const int lane = tid & 63;
    const int w    = tid >> 6;        // 0..7
    const int quad = lane >> 4;
    const int l15  = lane & 15;
    const int n0 = blockIdx.x * 32;
    const int m0 = blockIdx.y * 16;
    const int k0 = w * 128;

    // early: prefetch the Xproj additive term for this thread's output element
    const int om = tid >> 5;          // 0..15
    const int on = tid & 31;          // 0..31
    bf16* Hp = XH + ((size_t)t * B_SZ + m0 + om) * N_SZ + n0 + on;
    bf16 xv = *Hp;

    // A fragments: rows m0+l15 of H_{t-1}, k in [k0, k0+128)
    const bf16* Ap = XH + ((size_t)(t - 1) * B_SZ + m0 + l15) * N_SZ + k0 + quad * 8;
    bf16x8 areg[4];
#pragma unroll
    for (int kc = 0; kc < 4; ++kc)
        areg[kc] = *(const bf16x8*)&Ap[kc * 32];

    f32x4 z = {0.f, 0.f, 0.f, 0.f};
    f32x4 acc[2] = {z, z};
    const bf16* Bp = Wht + (size_t)(n0 + l15) * N_SZ + k0 + quad * 8;
#pragma unroll
    for (int nt = 0; nt < 2; ++nt)
#pragma unroll
        for (int kc = 0; kc < 4; ++kc) {
            bf16x8 b = *(const bf16x8*)&Bp[(size_t)(nt * 16) * N_SZ + kc * 32];
            acc[nt] = __builtin_amdgcn_mfma_f32_16x16x32_bf16(areg[kc], b, acc[nt], 0, 0, 0);
        }

    // K-reduction across 8 waves via LDS
#pragma unroll
    for (int nt = 0; nt < 2; ++nt)
#pragma unroll
        for (int r = 0; r < 4; ++r)
            red[(w * 16 + quad * 4 + r) * RST + nt * 16 + l15] = acc[nt][r];
    __syncthreads();

    float s = 0.f;
#pragma unroll
    for (int w2 = 0; w2 < 8; ++w2)
        s += red[(w2 * 16 + om) * RST + on];
    s += (float)xv;
    *Hp = (bf16)fast_tanh(s);
}

// ---------------- fused logits + log-softmax + loss (Wot in registers) ----------------
// Grid 256 blocks x 1024 threads (16 waves = 4 n-groups x 4 k-groups).
// Wave (ng,kg): B slab = vocab rows [ng*64,+64), k [kg*256,+256) in 128 VGPRs.
// Per 16-row chunk: A staged to LDS (reg-prefetched), 32 MFMAs/wave, K-reduce via
// ds_add_f32 into logits buffer, then wave-per-row softmax with float4 + shuffles.
__global__ __launch_bounds__(1024) void k_loss(
    const bf16* __restrict__ XH,
    const bf16* __restrict__ Wot,    // 256 x 1024 = Wout^T
    const float* __restrict__ ob,
    const float* __restrict__ labels,
    float* __restrict__ out)
{
    __shared__ __align__(16) bf16 As[16 * AST];   // 33.0 KB
    __shared__ float red[16 * CST];               // 16.6 KB (logits accumulator)
    __shared__ float ltot[16];

    const int tid  = threadIdx.x;
    const int lane = tid & 63;
    const int w    = tid >> 6;       // 0..15
    const int ng   = w & 3;
    const int kg   = w >> 2;
    const int quad = lane >> 4;
    const int l15  = lane & 15;
    const int blk  = blockIdx.x;

    // ---- B slab into registers: breg[nt][kc] ----
    bf16x8 breg[4][8];
#pragma unroll
    for (int nt = 0; nt < 4; ++nt)
#pragma unroll
        for (int kc = 0; kc < 8; ++kc)
            breg[nt][kc] = *(const bf16x8*)&Wot[(size_t)(ng * 64 + nt * 16 + l15) * N_SZ
                                                + kg * 256 + kc * 32 + quad * 8];

    const float4 ob4 = *(const float4*)&ob[lane * 4];

    // zero logits accumulator
    for (int i = tid; i < 16 * CST; i += 1024) red[i] = 0.f;

    // prefetch chunk 0
    const int prow = tid >> 6;          // 0..15
    const int pcol = (tid & 63) * 16;   // 0..1008
    const bf16* Ag = XH + (size_t)blk * 128 * N_SZ;
    bf16x8 pa0 = *(const bf16x8*)&Ag[(size_t)prow * N_SZ + pcol];
    bf16x8 pa1 = *(const bf16x8*)&Ag[(size_t)prow * N_SZ + pcol + 8];
    __syncthreads();

    float wtot = 0.f;
    for (int c = 0; c < 8; ++c) {
        // stage A for chunk c
        *(bf16x8*)&As[prow * AST + pcol]     = pa0;
        *(bf16x8*)&As[prow * AST + pcol + 8] = pa1;
        __syncthreads();

        // prefetch chunk c+1
        if (c < 7) {
            const bf16* Agn = XH + (size_t)(blk * 128 + (c + 1) * 16) * N_SZ;
            pa0 = *(const bf16x8*)&Agn[(size_t)prow * N_SZ + pcol];
            pa1 = *(const bf16x8*)&Agn[(size_t)prow * N_SZ + pcol + 8];
        }

        // MFMA phase: A frags for this wave's k-slice
        bf16x8 af[8];
#pragma unroll
        for (int kc = 0; kc < 8; ++kc)
            af[kc] = *(const bf16x8*)&As[l15 * AST + kg * 256 + kc * 32 + quad * 8];

        f32x4 z = {0.f, 0.f, 0.f, 0.f};
        f32x4 acc[4] = {z, z, z, z};
#pragma unroll
        for (int kc = 0; kc < 8; ++kc)
#pragma unroll
            for (int nt = 0; nt < 4; ++nt)
                acc[nt] = __builtin_amdgcn_mfma_f32_16x16x32_bf16(
                    af[kc], breg[nt][kc], acc[nt], 0, 0, 0);

        // K-reduce via LDS float atomics into logits buffer
#pragma unroll
        for (int nt = 0; nt < 4; ++nt)
#pragma unroll
            for (int r = 0; r < 4; ++r)
                atomicAdd(&red[(quad * 4 + r) * CST + ng * 64 + nt * 16 + l15], acc[nt][r]);
        __syncthreads();

        // softmax: wave w handles chunk-row w; lane covers cols [lane*4, +4)
        {
            float4 lv = *(const float4*)&red[w * CST + lane * 4];
            lv.x += ob4.x; lv.y += ob4.y; lv.z += ob4.z; lv.w += ob4.w;
            float mx = fmaxf(fmaxf(lv.x, lv.y), fmaxf(lv.z, lv.w));
#pragma unroll
            for (int s = 1; s < 64; s <<= 1)
                mx = fmaxf(mx, __shfl_xor(mx, s, 64));
            float sume = __expf(lv.x - mx) + __expf(lv.y - mx)
                       + __expf(lv.z - mx) + __expf(lv.w - mx);
            const float4 lb = *(const float4*)&labels[
                (size_t)(blk * 128 + c * 16 + w) * V_SZ + lane * 4];
            float labs = lb.x + lb.y + lb.z + lb.w;
            float labv = lb.x * lv.x + lb.y * lv.y + lb.z * lv.z + lb.w * lv.w;
#pragma unroll
            for (int s = 1; s < 64; s <<= 1) {
                sume += __shfl_xor(sume, s, 64);
                labs += __shfl_xor(labs, s, 64);
                labv += __shfl_xor(labv, s, 64);
            }
            float lse = mx + __logf(sume);
            wtot += labs * lse - labv;
            // zero logits row for next chunk
            float4 zz = {0.f, 0.f, 0.f, 0.f};
            *(float4*)&red[w * CST + lane * 4] = zz;
        }
        __syncthreads();
    }

    if (lane == 0) ltot[w] = wtot;
    __syncthreads();
    if (tid == 0) {
        float s = 0.f;
#pragma unroll
        for (int i = 0; i < 16; ++i) s += ltot[i];
        atomicAdd(out, s * (1.0f / (float)NROWS));
    }
}

extern "C" void kernel_launch(void* const* d_in, const int* in_sizes, int n_in,
                              void* d_out, int out_size, void* d_ws, size_t ws_size,
                              hipStream_t stream)
{
    const float* inputs  = (const float*)d_in[0];
    const float* labels  = (const float*)d_in[1];
    const float* weights = (const float*)d_in[2];
    const float* bias    = (const float*)d_in[3];
    const float* out_w   = (const float*)d_in[4];
    const float* out_b   = (const float*)d_in[5];
    float* out = (float*)d_out;

    char* ws = (char*)d_ws;
    bf16* XH  = (bf16*)ws;  ws += (size_t)NROWS * N_SZ * 2;   // 64 MB, Xproj then H in place
    bf16* Xb  = (bf16*)ws;  ws += (size_t)NROWS * V_SZ * 2;   // 16 MB
    bf16* Wxt = (bf16*)ws;  ws += (size_t)N_SZ * V_SZ * 2;    // 0.5 MB (Wx^T: 1024x256)
    bf16* Wht = (bf16*)ws;  ws += (size_t)N_SZ * N_SZ * 2;    // 2 MB   (Wh^T: 1024x1024)
    bf16* Wot = (bf16*)ws;  ws += (size_t)V_SZ * N_SZ * 2;    // 0.5 MB (Wo^T: 256x1024)

    hipMemsetAsync(out, 0, sizeof(float), stream);

    k_convert<<<dim3(NROWS * V_SZ / 1024), 256, 0, stream>>>(inputs, Xb, NROWS * V_SZ);
    k_transpose_cvt<<<dim3(N_SZ / 32, V_SZ / 32), 256, 0, stream>>>(weights, Wxt, V_SZ, N_SZ);
    k_transpose_cvt<<<dim3(N_SZ / 32, N_SZ / 32), 256, 0, stream>>>(
        weights + (size_t)V_SZ * N_SZ, Wht, N_SZ, N_SZ);
    k_transpose_cvt<<<dim3(V_SZ / 32, N_SZ / 32), 256, 0, stream>>>(out_w, Wot, N_SZ, V_SZ);

    k_xproj<<<dim3(NROWS / 64, N_SZ / 64), 256, 0, stream>>>(Xb, Wxt, bias, XH);

    for (int t = 1; t < T_STEPS; ++t)
        k_step<<<dim3(N_SZ / 32, B_SZ / 16), 512, 0, stream>>>(Wht, XH, t);

    k_loss<<<dim3(NROWS / 128), 1024, 0, stream>>>(XH, Wot, out_b, labels, out);
}